// Round 11
// baseline (69.949 us; speedup 1.0000x reference)
//
#include <hip/hip_runtime.h>
#include <math.h>

#define BSZ   32
#define SEQL  2048
#define TN    32
#define ENCD  512
#define HIDD  512
#define JW    29            // TN - 3
#define NW    (BSZ * JW)    // 928 windows

typedef short bf16x8 __attribute__((ext_vector_type(8)));
typedef float f32x4  __attribute__((ext_vector_type(4)));

__device__ __forceinline__ float sigm(float x) { return 1.f / (1.f + expf(-x)); }

__device__ __forceinline__ unsigned short f2bf(float x) {
    union { float f; unsigned u; } v; v.f = x;
    unsigned u = v.u;
    u += 0x7FFF + ((u >> 16) & 1);          // RNE
    return (unsigned short)(u >> 16);
}
__device__ __forceinline__ float bf2f(short s) {
    union { unsigned u; float f; } v; v.u = ((unsigned)(unsigned short)s) << 16;
    return v.f;
}

#define GLOAD_LDS16(gp, lp)                                                    \
    __builtin_amdgcn_global_load_lds(                                          \
        (const __attribute__((address_space(1))) void*)(gp),                   \
        (__attribute__((address_space(3))) void*)(lp), 16, 0, 0)

// ---------------- 1. prep: pooling + tscore (blocks 0..1023), weight conv ----
__global__ __launch_bounds__(512) void prep_k(const float* __restrict__ enc,
                                              const int* __restrict__ end_ids,
                                              short* __restrict__ tsbf,
                                              const float* __restrict__ w1,
                                              const float* __restrict__ w2,
                                              short* __restrict__ o1,
                                              short* __restrict__ o2,
                                              const float* __restrict__ fcw,
                                              float* __restrict__ tsc) {
    int tid = threadIdx.x;
    int bid = blockIdx.x;
    if (bid >= 1024) {
        int idx = (bid - 1024) * 512 + tid;             // 262144 chunks of 8 floats
        int t = idx >> 17;
        int i = idx & 131071;
        const float* s = (t ? w2 : w1) + (size_t)i * 8;
        short* o = (t ? o2 : o1) + (size_t)i * 8;
        float4 a = ((const float4*)s)[0];
        float4 b = ((const float4*)s)[1];
        union { short v[8]; bf16x8 p; } r;
        r.v[0] = (short)f2bf(a.x); r.v[1] = (short)f2bf(a.y);
        r.v[2] = (short)f2bf(a.z); r.v[3] = (short)f2bf(a.w);
        r.v[4] = (short)f2bf(b.x); r.v[5] = (short)f2bf(b.y);
        r.v[6] = (short)f2bf(b.z); r.v[7] = (short)f2bf(b.w);
        *(bf16x8*)o = r.p;
        return;
    }
    // ---- ragged segment-mean pooling, block = turn (b*TN + j)
    int j = bid & 31;
    int b = bid >> 5;
    int e_end   = end_ids[bid];
    int e_start = j ? (end_ids[bid - 1] + 1) : 0;
    int col = (tid & 127) << 2;
    int tr  = tid >> 7;                 // 0..3 token groups
    const float* base = enc + (size_t)b * SEQL * ENCD + col;
    float ax = 0.f, ay = 0.f, az = 0.f, aw = 0.f;
    float bx = 0.f, by = 0.f, bz = 0.f, bw = 0.f;
    for (int t = e_start + tr; t <= e_end; t += 8) {
        float4 v = *(const float4*)(base + (size_t)t * ENCD);
        ax += v.x; ay += v.y; az += v.z; aw += v.w;
        int t2 = t + 4;
        if (t2 <= e_end) {
            float4 u = *(const float4*)(base + (size_t)t2 * ENCD);
            bx += u.x; by += u.y; bz += u.z; bw += u.w;
        }
    }
    ax += bx; ay += by; az += bz; aw += bw;
    __shared__ float4 part[3][128];
    __shared__ float red[128];
    if (tr) part[tr - 1][tid & 127] = make_float4(ax, ay, az, aw);
    __syncthreads();
    if (!tr) {
        float4 p0 = part[0][tid], p1 = part[1][tid], p2 = part[2][tid];
        float inv = 1.f / (float)(e_end - e_start + 1);
        float mx = (ax + p0.x + p1.x + p2.x) * inv;
        float my = (ay + p0.y + p1.y + p2.y) * inv;
        float mz = (az + p0.z + p1.z + p2.z) * inv;
        float mw = (aw + p0.w + p1.w + p2.w) * inv;
        union { unsigned short v[4]; uint2 p; } q;
        q.v[0] = f2bf(mx); q.v[1] = f2bf(my); q.v[2] = f2bf(mz); q.v[3] = f2bf(mw);
        *(uint2*)(tsbf + (size_t)bid * ENCD + col) = q.p;
        float4 wv = *(const float4*)(fcw + HIDD + col);      // tgt half of fc_w
        red[tid] = mx * wv.x + my * wv.y + mz * wv.z + mw * wv.w;
    }
    __syncthreads();
    if (tid < 64) {
        float s = red[tid] + red[tid + 64];
#pragma unroll
        for (int sh = 32; sh; sh >>= 1) s += __shfl_down(s, sh, 64);
        if (tid == 0) tsc[bid] = s;
    }
}

// ---------------- 2. fused GEMM + LSTM step: A in registers, B in LDS --------
// Tile: 64 rows x 16 hcols (x4 gates = 64 B-rows). Grid dim3(32,16) = 512
// blocks, 256 threads, LDS 64 KB -> 2 blocks/CU. All A data (16x16B/thread)
// loaded to REGISTERS up front (static indexing), B panel staged to LDS once;
// ONE __syncthreads; then the K-loop is pure ds_read+MFMA with no barriers
// and no staging -- the L3 first-touch latency is paid once, not 8x.
template <int STEP>
__global__ __launch_bounds__(256) void gemm_lstm(const short* __restrict__ A,
                                                 const short* __restrict__ B,
                                                 ushort4* __restrict__ XWq,
                                                 float* __restrict__ Cb,
                                                 short* __restrict__ Hout,
                                                 float* __restrict__ ss_part,
                                                 const float* __restrict__ b_ih,
                                                 const float* __restrict__ b_hh,
                                                 const float* __restrict__ fcw) {
    __shared__ short Bpanel[64 * 512];     // 64 KB, K-resident
    int tid = threadIdx.x, w = tid >> 6, lane = tid & 63;
    int l15 = lane & 15, l4 = lane >> 4;
    int m0 = blockIdx.y * 64, hcol0 = blockIdx.x * 16;
    int hcol = hcol0 + l15;

    // ---- A straight to registers: row m0+w*16+l15, chunks [t][kk]
    int arow = m0 + w * 16 + l15;
    const short* Arow = A + (size_t)arow * 512;
    bf16x8 areg[8][2];
#pragma unroll
    for (int t = 0; t < 8; ++t)
#pragma unroll
        for (int kk = 0; kk < 2; ++kk)
            areg[t][kk] = *(const bf16x8*)(Arow + t * 64 + (kk * 4 + l4) * 8);

    // ---- stage the whole B panel (16 rows per wave, 1 KB each)
#pragma unroll
    for (int i = 0; i < 16; ++i) {
        int r = w * 16 + i;                            // panel row = g*16+hr
        int grow = (r >> 4) * 512 + hcol0 + (r & 15);  // B row = gate*512+hcol
        int scol = lane ^ (r & 7);                     // src slot for LDS slot=lane
        GLOAD_LDS16(B + (size_t)grow * 512 + scol * 8, &Bpanel[r * 512]);
    }
    __syncthreads();                                   // single drain + barrier

    f32x4 acc[4] = {};
#pragma unroll
    for (int t = 0; t < 8; ++t) {
        bf16x8 bfr[4][2];
#pragma unroll
        for (int kk = 0; kk < 2; ++kk)
#pragma unroll
            for (int g = 0; g < 4; ++g) {
                int rr = g * 16 + l15;                 // B panel row
                int s2 = t * 8 + ((kk * 4 + l4) ^ (rr & 7));
                bfr[g][kk] = *(const bf16x8*)&Bpanel[rr * 512 + s2 * 8];
            }
#pragma unroll
        for (int kk = 0; kk < 2; ++kk)
#pragma unroll
            for (int g = 0; g < 4; ++g)
                acc[g] = __builtin_amdgcn_mfma_f32_16x16x32_bf16(
                    areg[t][kk], bfr[g][kk], acc[g], 0, 0, 0);
    }

    // ---- epilogue: in-register LSTM (+ score partial in step 3)
    float bb0, bb1, bb2, bb3;
    if (STEP == 1) {
        bb0 = b_ih[hcol]        + b_hh[hcol];
        bb1 = b_ih[512 + hcol]  + b_hh[512 + hcol];
        bb2 = b_ih[1024 + hcol] + b_hh[1024 + hcol];
        bb3 = b_ih[1536 + hcol] + b_hh[1536 + hcol];
    }
    float hreg[4];
#pragma unroll
    for (int r = 0; r < 4; ++r) {
        int row = m0 + w * 16 + l4 * 4 + r;
        float gi = acc[0][r], gf = acc[1][r];
        float gg = acc[2][r], go = acc[3][r];
        float cn;
        if (STEP == 1) {
            gi += bb0; gf += bb1; gg += bb2; go += bb3;
            ushort4 q;
            q.x = f2bf(gi); q.y = f2bf(gf); q.z = f2bf(gg); q.w = f2bf(go);
            XWq[(size_t)row * 512 + hcol] = q;
            cn = sigm(gi) * tanhf(gg);              // c0 = 0
        } else {
            int xr = row + (STEP - 1); if (xr > 1023) xr = 1023;
            ushort4 q = XWq[(size_t)xr * 512 + hcol];
            gi += bf2f((short)q.x); gf += bf2f((short)q.y);
            gg += bf2f((short)q.z); go += bf2f((short)q.w);
            cn = sigm(gf) * Cb[(size_t)row * 512 + hcol] + sigm(gi) * tanhf(gg);
        }
        float h = sigm(go) * tanhf(cn);
        if (STEP < 3) {
            Cb[(size_t)row * 512 + hcol] = cn;
            Hout[(size_t)row * 512 + hcol] = (short)f2bf(h);
        } else {
            hreg[r] = h;
        }
    }
    if (STEP == 3) {
        // score partial over this block's 16 hcols; direct per-wave reduce
        float fcv = fcw[hcol];
#pragma unroll
        for (int r = 0; r < 4; ++r) {
            float v = hreg[r] * fcv;
#pragma unroll
            for (int m = 1; m < 16; m <<= 1) v += __shfl_xor(v, m, 64);
            if (l15 == 0) {
                int row = m0 + w * 16 + l4 * 4 + r;
                ss_part[(size_t)row * 32 + blockIdx.x] = v;
            }
        }
    }
}

// ---------------- 3. loss ----------------
__global__ __launch_bounds__(1024) void loss_k(const float* __restrict__ ss_part,
                                               const float* __restrict__ tsc,
                                               const float* __restrict__ fcb,
                                               float* __restrict__ out) {
    int tid = threadIdx.x;
    float l = 0.f;
    if (tid < NW) {
        int b = tid / JW, j = tid - (tid / JW) * JW;
        int turn = b * TN + j;
        const float* sp = ss_part + (size_t)turn * 32;
        float s = 0.f;
#pragma unroll
        for (int k = 0; k < 32; ++k) s += sp[k];
        float base = s + fcb[0];
        int nv = JW - j;
        const float* tp = tsc + b * TN + j + 3;
        float m = -1e30f, l0 = 0.f;
        for (int k = 0; k < nv; ++k) {
            float lg = base + tp[k];
            if (k == 0) l0 = lg;
            m = fmaxf(m, lg);
        }
        float sum = 0.f;
        for (int k = 0; k < nv; ++k) sum += expf(base + tp[k] - m);
        l = (m + logf(sum)) - l0;
    }
    __shared__ float red[16];
#pragma unroll
    for (int s = 32; s; s >>= 1) l += __shfl_down(l, s, 64);
    int wid = tid >> 6, lane = tid & 63;
    if (lane == 0) red[wid] = l;
    __syncthreads();
    if (tid == 0) {
        float tot = 0.f;
        for (int i = 0; i < 16; ++i) tot += red[i];
        out[0] = tot / (float)NW;
    }
}

extern "C" void kernel_launch(void* const* d_in, const int* in_sizes, int n_in,
                              void* d_out, int out_size, void* d_ws, size_t ws_size,
                              hipStream_t stream) {
    const float* enc     = (const float*)d_in[0];
    const int*   end_ids = (const int*)d_in[1];
    const float* W_ih    = (const float*)d_in[2];
    const float* W_hh    = (const float*)d_in[3];
    const float* b_ih    = (const float*)d_in[4];
    const float* b_hh    = (const float*)d_in[5];
    const float* fc_w    = (const float*)d_in[6];
    const float* fc_b    = (const float*)d_in[7];
    float* out = (float*)d_out;

    short* tsbf   = (short*)d_ws;              // 1024*512 bf16
    short* Wih_bf = tsbf + 1024 * 512;         // 2048*512
    short* Whh_bf = Wih_bf + 2048 * 512;       // 2048*512
    short* HA     = Whh_bf + 2048 * 512;       // 1024*512
    short* HB     = HA + 1024 * 512;           // 1024*512
    ushort4* XWq  = (ushort4*)(HB + 1024 * 512);   // 1024*512 ushort4
    float* Cb     = (float*)(XWq + 1024 * 512);    // 1024*512 f32
    float* ss_part = Cb + 1024 * 512;          // 1024*32 f32
    float* tsc    = ss_part + 1024 * 32;       // 1024 f32

    // 1. pooling -> tsbf + tsc; weights -> bf16
    prep_k<<<1536, 512, 0, stream>>>(enc, end_ids, tsbf, W_ih, W_hh,
                                     Wih_bf, Whh_bf, fc_w, tsc);
    // 2. step 1: gates = ts@Wih^T + bias -> XWq(bf16), h1->HA, c1->Cb
    gemm_lstm<1><<<dim3(32, 16), 256, 0, stream>>>(tsbf, Wih_bf, XWq, Cb, HA,
                                                   nullptr, b_ih, b_hh, fc_w);
    // 3. step 2: gates = h1@Whh^T + XWq[r+1]
    gemm_lstm<2><<<dim3(32, 16), 256, 0, stream>>>(HA, Whh_bf, XWq, Cb, HB,
                                                   nullptr, b_ih, b_hh, fc_w);
    // 4. step 3: gates = h2@Whh^T + XWq[r+2]; score partials in epilogue
    gemm_lstm<3><<<dim3(32, 16), 256, 0, stream>>>(HB, Whh_bf, XWq, Cb, nullptr,
                                                   ss_part, b_ih, b_hh, fc_w);
    // 5. loss
    loss_k<<<1, 1024, 0, stream>>>(ss_part, tsc, fc_b, out);
}

// Round 13
// 66.421 us; speedup vs baseline: 1.0531x; 1.0531x over previous
//
#include <hip/hip_runtime.h>
#include <math.h>

#define BSZ   32
#define SEQL  2048
#define TN    32
#define ENCD  512
#define HIDD  512
#define JW    29            // TN - 3
#define NW    (BSZ * JW)    // 928 windows

typedef short bf16x8 __attribute__((ext_vector_type(8)));
typedef float f32x4  __attribute__((ext_vector_type(4)));

__device__ __forceinline__ float sigm(float x) { return 1.f / (1.f + expf(-x)); }

__device__ __forceinline__ unsigned short f2bf(float x) {
    union { float f; unsigned u; } v; v.f = x;
    unsigned u = v.u;
    u += 0x7FFF + ((u >> 16) & 1);          // RNE
    return (unsigned short)(u >> 16);
}
__device__ __forceinline__ float bf2f(short s) {
    union { unsigned u; float f; } v; v.u = ((unsigned)(unsigned short)s) << 16;
    return v.f;
}

#define GLOAD_LDS16(gp, lp)                                                    \
    __builtin_amdgcn_global_load_lds(                                          \
        (const __attribute__((address_space(1))) void*)(gp),                   \
        (__attribute__((address_space(3))) void*)(lp), 16, 0, 0)

// ---------------- 1. prep: pooling + tscore (blocks 0..1023), weight conv ----
__global__ __launch_bounds__(512) void prep_k(const float* __restrict__ enc,
                                              const int* __restrict__ end_ids,
                                              short* __restrict__ tsbf,
                                              const float* __restrict__ w1,
                                              const float* __restrict__ w2,
                                              short* __restrict__ o1,
                                              short* __restrict__ o2,
                                              const float* __restrict__ fcw,
                                              float* __restrict__ tsc) {
    int tid = threadIdx.x;
    int bid = blockIdx.x;
    if (bid >= 1024) {
        int idx = (bid - 1024) * 512 + tid;             // 262144 chunks of 8 floats
        int t = idx >> 17;
        int i = idx & 131071;
        const float* s = (t ? w2 : w1) + (size_t)i * 8;
        short* o = (t ? o2 : o1) + (size_t)i * 8;
        float4 a = ((const float4*)s)[0];
        float4 b = ((const float4*)s)[1];
        union { short v[8]; bf16x8 p; } r;
        r.v[0] = (short)f2bf(a.x); r.v[1] = (short)f2bf(a.y);
        r.v[2] = (short)f2bf(a.z); r.v[3] = (short)f2bf(a.w);
        r.v[4] = (short)f2bf(b.x); r.v[5] = (short)f2bf(b.y);
        r.v[6] = (short)f2bf(b.z); r.v[7] = (short)f2bf(b.w);
        *(bf16x8*)o = r.p;
        return;
    }
    // ---- ragged segment-mean pooling, block = turn (b*TN + j)
    int j = bid & 31;
    int b = bid >> 5;
    int e_end   = end_ids[bid];
    int e_start = j ? (end_ids[bid - 1] + 1) : 0;
    int col = (tid & 127) << 2;
    int tr  = tid >> 7;                 // 0..3 token groups
    const float* base = enc + (size_t)b * SEQL * ENCD + col;
    float ax = 0.f, ay = 0.f, az = 0.f, aw = 0.f;
    float bx = 0.f, by = 0.f, bz = 0.f, bw = 0.f;
    for (int t = e_start + tr; t <= e_end; t += 8) {
        float4 v = *(const float4*)(base + (size_t)t * ENCD);
        ax += v.x; ay += v.y; az += v.z; aw += v.w;
        int t2 = t + 4;
        if (t2 <= e_end) {
            float4 u = *(const float4*)(base + (size_t)t2 * ENCD);
            bx += u.x; by += u.y; bz += u.z; bw += u.w;
        }
    }
    ax += bx; ay += by; az += bz; aw += bw;
    __shared__ float4 part[3][128];
    __shared__ float red[128];
    if (tr) part[tr - 1][tid & 127] = make_float4(ax, ay, az, aw);
    __syncthreads();
    if (!tr) {
        float4 p0 = part[0][tid], p1 = part[1][tid], p2 = part[2][tid];
        float inv = 1.f / (float)(e_end - e_start + 1);
        float mx = (ax + p0.x + p1.x + p2.x) * inv;
        float my = (ay + p0.y + p1.y + p2.y) * inv;
        float mz = (az + p0.z + p1.z + p2.z) * inv;
        float mw = (aw + p0.w + p1.w + p2.w) * inv;
        union { unsigned short v[4]; uint2 p; } q;
        q.v[0] = f2bf(mx); q.v[1] = f2bf(my); q.v[2] = f2bf(mz); q.v[3] = f2bf(mw);
        *(uint2*)(tsbf + (size_t)bid * ENCD + col) = q.p;
        float4 wv = *(const float4*)(fcw + HIDD + col);      // tgt half of fc_w
        red[tid] = mx * wv.x + my * wv.y + mz * wv.z + mw * wv.w;
    }
    __syncthreads();
    if (tid < 64) {
        float s = red[tid] + red[tid + 64];
#pragma unroll
        for (int sh = 32; sh; sh >>= 1) s += __shfl_down(s, sh, 64);
        if (tid == 0) tsc[bid] = s;
    }
}

// ---------------- 2. fused GEMM + LSTM step (+ score in step 3) ----------------
// Tile: 32 rows x 32 hcols (x4 gates = 128 B-rows). Grid dim3(16,32) = 512
// blocks (~2/CU). 4 waves (2m x 2h). Per-wave: acc[gate 4] f32x4.
// LDS: A 2x4KB + B 2x16KB = 40 KB. Plain-__syncthreads 2-buffer K-loop
// (verified round-5 pattern; best measured total 66.7 us).
template <int STEP>
__global__ __launch_bounds__(256) void gemm_lstm(const short* __restrict__ A,
                                                 const short* __restrict__ B,
                                                 ushort4* __restrict__ XWq,
                                                 float* __restrict__ Cb,
                                                 short* __restrict__ Hout,
                                                 float* __restrict__ ss_part,
                                                 const float* __restrict__ b_ih,
                                                 const float* __restrict__ b_hh,
                                                 const float* __restrict__ fcw) {
    __shared__ short Als[2][4 * 512];      // 2 x 4 KB
    __shared__ short Bls[2][16 * 512];     // 2 x 16 KB
    int tid = threadIdx.x, w = tid >> 6, lane = tid & 63;
    int l15 = lane & 15, l4 = lane >> 4;
    int m0 = blockIdx.y * 32, hcol0 = blockIdx.x * 32;
    int wm = (w >> 1) * 16, wh = (w & 1) * 16;
    int hcol = hcol0 + wh + l15;
    const short* Aptr = A + (size_t)m0 * 512;
    f32x4 acc[4] = {};

    auto stage = [&](int sel, int k0) {
#pragma unroll
        for (int i = 0; i < 5; ++i) {
            int c = w * 5 + i;
            if (c < 4) {                               // A: 4 chunks of 1 KB
                int unit = c * 64 + lane;
                int row = unit >> 3, slot = unit & 7;
                int scol = slot ^ (row & 7);
                GLOAD_LDS16(Aptr + (size_t)row * 512 + k0 + scol * 8,
                            &Als[sel][c * 512]);
            } else {                                   // B: 16 chunks
                int cc = c - 4;
                int unit = cc * 64 + lane;
                int rr = unit >> 3, slot = unit & 7;
                int grow = (rr >> 5) * 512 + hcol0 + (rr & 31);
                int scol = slot ^ (rr & 7);
                GLOAD_LDS16(B + (size_t)grow * 512 + k0 + scol * 8,
                            &Bls[sel][cc * 512]);
            }
        }
    };

    stage(0, 0);
    __syncthreads();
    int sel = 0;
    for (int t = 0; t < 8; ++t) {
        if (t < 7) stage(sel ^ 1, (t + 1) * 64);
        bf16x8 af[2], bfr[4][2];
#pragma unroll
        for (int kk = 0; kk < 2; ++kk) {
            int row = wm + l15;
            int s = (kk * 4 + l4) ^ (row & 7);
            af[kk] = *(const bf16x8*)&Als[sel][row * 64 + s * 8];
#pragma unroll
            for (int g = 0; g < 4; ++g) {
                int rr = g * 32 + wh + l15;
                int s2 = (kk * 4 + l4) ^ (rr & 7);
                bfr[g][kk] = *(const bf16x8*)&Bls[sel][rr * 64 + s2 * 8];
            }
        }
#pragma unroll
        for (int kk = 0; kk < 2; ++kk)
#pragma unroll
            for (int g = 0; g < 4; ++g)
                acc[g] = __builtin_amdgcn_mfma_f32_16x16x32_bf16(
                    af[kk], bfr[g][kk], acc[g], 0, 0, 0);
        __syncthreads();
        sel ^= 1;
    }

    // ---- epilogue: in-register LSTM (+ score partial in step 3)
    float bb0, bb1, bb2, bb3;
    if (STEP == 1) {
        bb0 = b_ih[hcol]        + b_hh[hcol];
        bb1 = b_ih[512 + hcol]  + b_hh[512 + hcol];
        bb2 = b_ih[1024 + hcol] + b_hh[1024 + hcol];
        bb3 = b_ih[1536 + hcol] + b_hh[1536 + hcol];
    }
    float hreg[4];
#pragma unroll
    for (int r = 0; r < 4; ++r) {
        int row = m0 + wm + l4 * 4 + r;
        float gi = acc[0][r], gf = acc[1][r];
        float gg = acc[2][r], go = acc[3][r];
        float cn;
        if (STEP == 1) {
            gi += bb0; gf += bb1; gg += bb2; go += bb3;
            ushort4 q;
            q.x = f2bf(gi); q.y = f2bf(gf); q.z = f2bf(gg); q.w = f2bf(go);
            XWq[(size_t)row * 512 + hcol] = q;
            cn = sigm(gi) * tanhf(gg);              // c0 = 0
        } else {
            int xr = row + (STEP - 1); if (xr > 1023) xr = 1023;
            ushort4 q = XWq[(size_t)xr * 512 + hcol];
            gi += bf2f((short)q.x); gf += bf2f((short)q.y);
            gg += bf2f((short)q.z); go += bf2f((short)q.w);
            cn = sigm(gf) * Cb[(size_t)row * 512 + hcol] + sigm(gi) * tanhf(gg);
        }
        float h = sigm(go) * tanhf(cn);
        if (STEP < 3) {
            Cb[(size_t)row * 512 + hcol] = cn;
            Hout[(size_t)row * 512 + hcol] = (short)f2bf(h);
        } else {
            hreg[r] = h;
        }
    }
    if (STEP == 3) {
        // per-block sscore partial over its 32 hcols
        float fcv = fcw[hcol];
        float* sred = (float*)&Als[0][0];          // k-loop done, LDS reusable
        float vals[4];
#pragma unroll
        for (int r = 0; r < 4; ++r) {
            float v = hreg[r] * fcv;
#pragma unroll
            for (int m = 1; m < 16; m <<= 1) v += __shfl_xor(v, m, 64);
            vals[r] = v;
        }
        __syncthreads();
        if ((w & 1) == 0 && l15 == 0)
#pragma unroll
            for (int r = 0; r < 4; ++r) sred[wm + l4 * 4 + r] = vals[r];
        __syncthreads();
        if ((w & 1) == 1 && l15 == 0)
#pragma unroll
            for (int r = 0; r < 4; ++r) sred[wm + l4 * 4 + r] += vals[r];
        __syncthreads();
        if (tid < 32) ss_part[(size_t)(m0 + tid) * 16 + blockIdx.x] = sred[tid];
    }
}

// ---------------- 3. loss ----------------
__global__ __launch_bounds__(1024) void loss_k(const float* __restrict__ ss_part,
                                               const float* __restrict__ tsc,
                                               const float* __restrict__ fcb,
                                               float* __restrict__ out) {
    int tid = threadIdx.x;
    float l = 0.f;
    if (tid < NW) {
        int b = tid / JW, j = tid - (tid / JW) * JW;
        int turn = b * TN + j;
        const float* sp = ss_part + (size_t)turn * 16;
        float s = 0.f;
#pragma unroll
        for (int k = 0; k < 16; ++k) s += sp[k];
        float base = s + fcb[0];
        int nv = JW - j;
        const float* tp = tsc + b * TN + j + 3;
        float m = -1e30f, l0 = 0.f;
        for (int k = 0; k < nv; ++k) {
            float lg = base + tp[k];
            if (k == 0) l0 = lg;
            m = fmaxf(m, lg);
        }
        float sum = 0.f;
        for (int k = 0; k < nv; ++k) sum += expf(base + tp[k] - m);
        l = (m + logf(sum)) - l0;
    }
    __shared__ float red[16];
#pragma unroll
    for (int s = 32; s; s >>= 1) l += __shfl_down(l, s, 64);
    int wid = tid >> 6, lane = tid & 63;
    if (lane == 0) red[wid] = l;
    __syncthreads();
    if (tid == 0) {
        float tot = 0.f;
        for (int i = 0; i < 16; ++i) tot += red[i];
        out[0] = tot / (float)NW;
    }
}

extern "C" void kernel_launch(void* const* d_in, const int* in_sizes, int n_in,
                              void* d_out, int out_size, void* d_ws, size_t ws_size,
                              hipStream_t stream) {
    const float* enc     = (const float*)d_in[0];
    const int*   end_ids = (const int*)d_in[1];
    const float* W_ih    = (const float*)d_in[2];
    const float* W_hh    = (const float*)d_in[3];
    const float* b_ih    = (const float*)d_in[4];
    const float* b_hh    = (const float*)d_in[5];
    const float* fc_w    = (const float*)d_in[6];
    const float* fc_b    = (const float*)d_in[7];
    float* out = (float*)d_out;

    short* tsbf   = (short*)d_ws;              // 1024*512 bf16
    short* Wih_bf = tsbf + 1024 * 512;         // 2048*512
    short* Whh_bf = Wih_bf + 2048 * 512;       // 2048*512
    short* HA     = Whh_bf + 2048 * 512;       // 1024*512
    short* HB     = HA + 1024 * 512;           // 1024*512
    ushort4* XWq  = (ushort4*)(HB + 1024 * 512);   // 1024*512 ushort4
    float* Cb     = (float*)(XWq + 1024 * 512);    // 1024*512 f32
    float* ss_part = Cb + 1024 * 512;          // 1024*16 f32
    float* tsc    = ss_part + 1024 * 16;       // 1024 f32

    // 1. pooling -> tsbf + tsc; weights -> bf16
    prep_k<<<1536, 512, 0, stream>>>(enc, end_ids, tsbf, W_ih, W_hh,
                                     Wih_bf, Whh_bf, fc_w, tsc);
    // 2. step 1: gates = ts@Wih^T + bias -> XWq(bf16), h1->HA, c1->Cb
    gemm_lstm<1><<<dim3(16, 32), 256, 0, stream>>>(tsbf, Wih_bf, XWq, Cb, HA,
                                                   nullptr, b_ih, b_hh, fc_w);
    // 3. step 2: gates = h1@Whh^T + XWq[r+1]
    gemm_lstm<2><<<dim3(16, 32), 256, 0, stream>>>(HA, Whh_bf, XWq, Cb, HB,
                                                   nullptr, b_ih, b_hh, fc_w);
    // 4. step 3: gates = h2@Whh^T + XWq[r+2]; score partials in epilogue
    gemm_lstm<3><<<dim3(16, 32), 256, 0, stream>>>(HB, Whh_bf, XWq, Cb, nullptr,
                                                   ss_part, b_ih, b_hh, fc_w);
    // 5. loss
    loss_k<<<1, 1024, 0, stream>>>(ss_part, tsc, fc_b, out);
}